// Round 1
// baseline (3264.807 us; speedup 1.0000x reference)
//
#include <hip/hip_runtime.h>
#include <cstddef>

#define BATCH   8
#define LSEQ    4096
#define DMODEL  128
#define DINNER  256
#define NSTATE  16
#define RDT     8
#define NLAYER  4
#define MROWS   (BATCH*LSEQ)   // 32768

__device__ __forceinline__ float silu_f(float v) { return v / (1.f + expf(-v)); }
__device__ __forceinline__ float softplus_f(float v) {
  return v > 20.f ? v : log1pf(expf(v));
}

// ---------------------------------------------------------------------------
// Generic tiled GEMM: C = A[M,K] @ W[N,K]^T
// mode 0: out0[m*N + n] = c
// mode 1: (N==512) n<256 -> out0[m*256+n] = c (raw xa); n>=256 -> out1[m*256+n-256] = silu(c)
// ---------------------------------------------------------------------------
__global__ __launch_bounds__(256) void gemm_awt(
    const float* __restrict__ A, const float* __restrict__ W,
    float* __restrict__ out0, float* __restrict__ out1,
    int M, int N, int K, int mode)
{
  __shared__ float As[32][68];
  __shared__ float Bs[32][68];
  const int m0 = blockIdx.x * 64;
  const int n0 = blockIdx.y * 64;
  const int t  = threadIdx.x;
  const int tx = t & 15, ty = t >> 4;
  const int kk_s = t & 31, row_s = t >> 5;   // staging: 32 k x 8 rows/pass

  float acc[4][4] = {};

  for (int k0 = 0; k0 < K; k0 += 32) {
#pragma unroll
    for (int p = 0; p < 8; ++p) {
      int r = row_s + p * 8;
      As[kk_s][r] = A[(size_t)(m0 + r) * K + (k0 + kk_s)];
      Bs[kk_s][r] = W[(size_t)(n0 + r) * K + (k0 + kk_s)];
    }
    __syncthreads();
#pragma unroll
    for (int kk = 0; kk < 32; ++kk) {
      float4 a4 = *(const float4*)&As[kk][ty * 4];
      float4 b4 = *(const float4*)&Bs[kk][tx * 4];
      float av[4] = {a4.x, a4.y, a4.z, a4.w};
      float bv[4] = {b4.x, b4.y, b4.z, b4.w};
#pragma unroll
      for (int i = 0; i < 4; ++i)
#pragma unroll
        for (int j = 0; j < 4; ++j)
          acc[i][j] = fmaf(av[i], bv[j], acc[i][j]);
    }
    __syncthreads();
  }

#pragma unroll
  for (int i = 0; i < 4; ++i) {
    int m = m0 + ty * 4 + i;
    float4 c4 = make_float4(acc[i][0], acc[i][1], acc[i][2], acc[i][3]);
    if (mode == 0) {
      *(float4*)&out0[(size_t)m * N + n0 + tx * 4] = c4;
    } else {
      int n = n0 + tx * 4;
      if (n < 256) {
        *(float4*)&out0[(size_t)m * 256 + n] = c4;
      } else {
        c4.x = silu_f(c4.x); c4.y = silu_f(c4.y);
        c4.z = silu_f(c4.z); c4.w = silu_f(c4.w);
        *(float4*)&out1[(size_t)m * 256 + (n - 256)] = c4;
      }
    }
  }
}

// ---------------------------------------------------------------------------
// Causal depthwise conv (k=4) + bias + silu, with [M,256] -> [B,256,L] transpose
// block: (l-tile 128, d-tile 64, b)
// ---------------------------------------------------------------------------
__global__ __launch_bounds__(256) void conv_silu_t(
    const float* __restrict__ xa_rm,   // [M,256] pre-conv (row-major)
    const float* __restrict__ cw,      // [256,4]
    const float* __restrict__ cb,      // [256]
    float* __restrict__ xa_t)          // [B,256,L]
{
  __shared__ float tile[64][133];      // [dd][li], li=0 ~ l0-3
  __shared__ float s_cw[64][4];
  __shared__ float s_cb[64];
  const int b  = blockIdx.z;
  const int d0 = blockIdx.y * 64;
  const int l0 = blockIdx.x * 128;
  const int t  = threadIdx.x;

  if (t < 64) {
    s_cb[t] = cb[d0 + t];
#pragma unroll
    for (int k = 0; k < 4; ++k) s_cw[t][k] = cw[(d0 + t) * 4 + k];
  }
  const int dd_st = t & 63;
  for (int li = t >> 6; li < 131; li += 4) {
    int l = l0 - 3 + li;
    float v = 0.f;
    if (l >= 0) v = xa_rm[((size_t)(b * LSEQ + l)) * 256 + d0 + dd_st];
    tile[dd_st][li] = v;
  }
  __syncthreads();

  for (int idx = t; idx < 64 * 128; idx += 256) {
    int dd = idx >> 7;        // 0..63
    int lc = idx & 127;       // 0..127
    float v = s_cb[dd]
            + tile[dd][lc + 0] * s_cw[dd][0]
            + tile[dd][lc + 1] * s_cw[dd][1]
            + tile[dd][lc + 2] * s_cw[dd][2]
            + tile[dd][lc + 3] * s_cw[dd][3];
    v = silu_f(v);
    xa_t[((size_t)(b * DINNER + d0 + dd)) * LSEQ + l0 + lc] = v;
  }
}

// ---------------------------------------------------------------------------
// Fused x_proj (40x256) + dt_proj (256x8) + softplus.
// block: (l-tile 64, b). Writes dt_t [B,256,L], Bb/Cb [B,L,16].
// ---------------------------------------------------------------------------
__global__ __launch_bounds__(256) void proj_dt(
    const float* __restrict__ xa_t,    // [B,256,L]
    const float* __restrict__ xp_w,    // [40,256]
    const float* __restrict__ dtp_w,   // [256,8]
    const float* __restrict__ dtp_b,   // [256]
    float* __restrict__ dt_t,          // [B,256,L]
    float* __restrict__ Bb,            // [B,L,16]
    float* __restrict__ Cb)            // [B,L,16]
{
  __shared__ float s_xpc[40][68];      // xp chunk [n][kk]
  __shared__ float s_dtw[256 * 8];
  __shared__ float s_dtb[256];
  __shared__ float s_xa[64][68];       // [ll][kk]
  __shared__ float s_proj[64][44];     // [ll][n]
  const int b  = blockIdx.y;
  const int l0 = blockIdx.x * 64;
  const int t  = threadIdx.x;

  for (int i = t; i < 256 * 8; i += 256) s_dtw[i] = dtp_w[i];
  s_dtb[t] = dtp_b[t];

  const int ll_st  = t & 63;
  const int kk0_st = t >> 6;
  const int kk_w   = t & 63;   // xp staging
  const int nb_w   = t >> 6;
  const int lA = t & 31;       // compute rows lA, lA+32
  const int g  = t >> 5;       // 0..7 -> n in [5g,5g+5)

  float acc0[5] = {}, acc1[5] = {};

  for (int kc = 0; kc < 256; kc += 64) {
    __syncthreads();
#pragma unroll
    for (int p = 0; p < 16; ++p) {
      int kk = kk0_st + p * 4;
      s_xa[ll_st][kk] =
          xa_t[((size_t)(b * DINNER + kc + kk)) * LSEQ + l0 + ll_st];
    }
#pragma unroll
    for (int p = 0; p < 10; ++p) {
      int n = nb_w + p * 4;    // 0..39
      s_xpc[n][kk_w] = xp_w[n * 256 + kc + kk_w];
    }
    __syncthreads();
#pragma unroll
    for (int kk = 0; kk < 64; kk += 4) {
      float4 a0 = *(const float4*)&s_xa[lA][kk];
      float4 a1 = *(const float4*)&s_xa[lA + 32][kk];
#pragma unroll
      for (int j = 0; j < 5; ++j) {
        float4 w4 = *(const float4*)&s_xpc[g * 5 + j][kk];
        acc0[j] = fmaf(a0.x, w4.x, fmaf(a0.y, w4.y,
                  fmaf(a0.z, w4.z, fmaf(a0.w, w4.w, acc0[j]))));
        acc1[j] = fmaf(a1.x, w4.x, fmaf(a1.y, w4.y,
                  fmaf(a1.z, w4.z, fmaf(a1.w, w4.w, acc1[j]))));
      }
    }
  }
  __syncthreads();
#pragma unroll
  for (int j = 0; j < 5; ++j) {
    s_proj[lA][g * 5 + j]      = acc0[j];
    s_proj[lA + 32][g * 5 + j] = acc1[j];
  }
  __syncthreads();

  const int ll = t & 63;
  const int dgroup = t >> 6;
  float4 p0 = *(const float4*)&s_proj[ll][0];
  float4 p1 = *(const float4*)&s_proj[ll][4];
  for (int j = 0; j < 64; ++j) {
    int dout = dgroup * 64 + j;
    float4 w0 = *(const float4*)&s_dtw[dout * 8];
    float4 w1 = *(const float4*)&s_dtw[dout * 8 + 4];
    float v = s_dtb[dout]
            + p0.x * w0.x + p0.y * w0.y + p0.z * w0.z + p0.w * w0.w
            + p1.x * w1.x + p1.y * w1.y + p1.z * w1.z + p1.w * w1.w;
    dt_t[((size_t)(b * DINNER + dout)) * LSEQ + l0 + ll] = softplus_f(v);
  }
  if (dgroup == 0) {
    size_t base = ((size_t)(b * LSEQ) + l0 + ll) * 16;
#pragma unroll
    for (int q = 0; q < 4; ++q)
      *(float4*)&Bb[base + q * 4] = *(const float4*)&s_proj[ll][8 + q * 4];
  } else if (dgroup == 1) {
    size_t base = ((size_t)(b * LSEQ) + l0 + ll) * 16;
#pragma unroll
    for (int q = 0; q < 4; ++q)
      *(float4*)&Cb[base + q * 4] = *(const float4*)&s_proj[ll][24 + q * 4];
  }
}

// ---------------------------------------------------------------------------
// Selective scan. 16 lanes (one per state n) per (b,d) channel; 4 channels/wave.
// grid: BATCH * DINNER/4 = 512 blocks of 64 threads.
// ---------------------------------------------------------------------------
__global__ __launch_bounds__(64) void scan_k(
    const float* __restrict__ dt_t, const float* __restrict__ u_t,
    const float* __restrict__ Bb,   const float* __restrict__ Cb,
    const float* __restrict__ A_log, const float* __restrict__ Dp,
    float* __restrict__ y_t)
{
  const int blk = blockIdx.x;
  const int b   = blk >> 6;              // /64
  const int d0  = (blk & 63) * 4;
  const int lane = threadIdx.x;
  const int g = lane >> 4;
  const int n = lane & 15;
  const int d = d0 + g;

  const float Aa = -expf(A_log[d * NSTATE + n]);
  const float Dv = Dp[d];
  const float* dtp = dt_t + ((size_t)(b * DINNER + d)) * LSEQ;
  const float* up  = u_t  + ((size_t)(b * DINNER + d)) * LSEQ;
  const float* Bp  = Bb + (size_t)b * LSEQ * NSTATE + n;
  const float* Cp  = Cb + (size_t)b * LSEQ * NSTATE + n;
  float* yp = y_t + ((size_t)(b * DINNER + d)) * LSEQ;

  float h = 0.f;
  for (int l = 0; l < LSEQ; l += 4) {
    float4 dt4 = *(const float4*)(dtp + l);
    float4 u4  = *(const float4*)(up + l);
    float dts[4] = {dt4.x, dt4.y, dt4.z, dt4.w};
    float us[4]  = {u4.x, u4.y, u4.z, u4.w};
    float bv[4], cv[4], ys[4];
#pragma unroll
    for (int s = 0; s < 4; ++s) {
      bv[s] = Bp[(size_t)(l + s) * NSTATE];
      cv[s] = Cp[(size_t)(l + s) * NSTATE];
    }
#pragma unroll
    for (int s = 0; s < 4; ++s) {
      float dA = expf(dts[s] * Aa);
      h = fmaf(dA, h, (dts[s] * us[s]) * bv[s]);
      float p = h * cv[s];
      p += __shfl_xor(p, 1);
      p += __shfl_xor(p, 2);
      p += __shfl_xor(p, 4);
      p += __shfl_xor(p, 8);
      ys[s] = fmaf(us[s], Dv, p);
    }
    if (n == 0) {
      *(float4*)(yp + l) = make_float4(ys[0], ys[1], ys[2], ys[3]);
    }
  }
}

// ---------------------------------------------------------------------------
// ymul[m,d] = y_t[b,d,l] * zs[m,d]   ([B,256,L] -> [M,256] transpose, fused mul)
// ---------------------------------------------------------------------------
__global__ __launch_bounds__(256) void transmul(
    const float* __restrict__ y_t, const float* __restrict__ zs,
    float* __restrict__ outA)
{
  __shared__ float tile[64][129];
  const int b  = blockIdx.z;
  const int d0 = blockIdx.y * 64;
  const int l0 = blockIdx.x * 128;
  const int t  = threadIdx.x;
  const int lc_st = t & 127;
  for (int dd = t >> 7; dd < 64; dd += 2)
    tile[dd][lc_st] = y_t[((size_t)(b * DINNER + d0 + dd)) * LSEQ + l0 + lc_st];
  __syncthreads();
  for (int idx = t; idx < 64 * 128; idx += 256) {
    int dd = idx & 63, lc = idx >> 6;
    size_t addr = ((size_t)(b * LSEQ) + l0 + lc) * DINNER + d0 + dd;
    outA[addr] = tile[dd][lc] * zs[addr];
  }
}

// ---------------------------------------------------------------------------
extern "C" void kernel_launch(void* const* d_in, const int* in_sizes, int n_in,
                              void* d_out, int out_size, void* d_ws, size_t ws_size,
                              hipStream_t stream) {
  const float* x_in  = (const float*)d_in[0];
  const float* w_in  = (const float*)d_in[1];   // [4,512,128]
  const float* cw    = (const float*)d_in[2];   // [4,256,4]
  const float* cb    = (const float*)d_in[3];   // [4,256]
  const float* xpw   = (const float*)d_in[4];   // [4,40,256]
  const float* dtw   = (const float*)d_in[5];   // [4,256,8]
  const float* dtb   = (const float*)d_in[6];   // [4,256]
  const float* alog  = (const float*)d_in[7];   // [4,256,16]
  const float* Dp    = (const float*)d_in[8];   // [4,256]
  const float* ow    = (const float*)d_in[9];   // [4,128,256]
  float* out = (float*)d_out;

  const size_t M = MROWS;
  float* f0 = (float*)d_ws;            // x ping  [M,128]
  float* f1 = f0 + M * 128;            // x pong  [M,128]
  float* f2 = f1 + M * 128;            // xa_pre row-major [M,256] -> later dt_t [B,256,L]
  float* f3 = f2 + M * 256;            // zs = silu(z) [M,256]
  float* f4 = f3 + M * 256;            // xa_t [B,256,L] -> later ymul [M,256]
  float* f6 = f4 + M * 256;            // Bb [B,L,16]
  float* f7 = f6 + M * 16;             // Cb [B,L,16]
  float* f8 = f7 + M * 16;             // y_t [B,256,L]

  const float* cur = x_in;
  for (int i = 0; i < NLAYER; ++i) {
    float* xout = (i == NLAYER - 1) ? out : ((i % 2 == 0) ? f0 : f1);
    const float* wi  = w_in + (size_t)i * 512 * 128;
    const float* cwi = cw   + (size_t)i * 256 * 4;
    const float* cbi = cb   + (size_t)i * 256;
    const float* xpi = xpw  + (size_t)i * 40 * 256;
    const float* dwi = dtw  + (size_t)i * 256 * 8;
    const float* dbi = dtb  + (size_t)i * 256;
    const float* ali = alog + (size_t)i * 256 * 16;
    const float* dpi = Dp   + (size_t)i * 256;
    const float* owi = ow   + (size_t)i * 128 * 256;

    // 1. in_proj: [M,128] @ [512,128]^T -> xa_pre(f2), silu(z)(f3)
    gemm_awt<<<dim3(MROWS / 64, 8), 256, 0, stream>>>(
        cur, wi, f2, f3, MROWS, 512, 128, 1);
    // 2. conv + silu + transpose -> xa_t (f4)
    conv_silu_t<<<dim3(LSEQ / 128, DINNER / 64, BATCH), 256, 0, stream>>>(
        f2, cwi, cbi, f4);
    // 3. x_proj + dt_proj + softplus -> dt_t (f2), Bb (f6), Cb (f7)
    proj_dt<<<dim3(LSEQ / 64, BATCH), 256, 0, stream>>>(
        f4, xpi, dwi, dbi, f2, f6, f7);
    // 4. selective scan -> y_t (f8)
    scan_k<<<dim3(BATCH * DINNER / 4), 64, 0, stream>>>(
        f2, f4, f6, f7, ali, dpi, f8);
    // 5. y * silu(z), transpose back -> ymul (f4)
    transmul<<<dim3(LSEQ / 128, DINNER / 64, BATCH), 256, 0, stream>>>(
        f8, f3, f4);
    // 6. out_proj: [M,256] @ [128,256]^T -> xout
    gemm_awt<<<dim3(MROWS / 64, 2), 256, 0, stream>>>(
        f4, owi, xout, nullptr, MROWS, 128, 256, 0);

    cur = xout;
  }
}

// Round 3
// 2300.763 us; speedup vs baseline: 1.4190x; 1.4190x over previous
//
#include <hip/hip_runtime.h>
#include <cstddef>

#define BATCH   8
#define LSEQ    4096
#define DMODEL  128
#define DINNER  256
#define NSTATE  16
#define NLAYER  4
#define MROWS   (BATCH*LSEQ)   // 32768

__device__ __forceinline__ float silu_f(float v) { return v / (1.f + expf(-v)); }
__device__ __forceinline__ float softplus_f(float v) {
  return v > 20.f ? v : log1pf(expf(v));
}

// ---------------------------------------------------------------------------
// Generic tiled GEMM: C = A[M,K] @ W[N,K]^T
// mode 0: out0[m*N + n] = c
// mode 1: (N==512) n<256 -> out0[m*256+n] = c (raw xa); n>=256 -> out1 = silu(c)
// ---------------------------------------------------------------------------
__global__ __launch_bounds__(256) void gemm_awt(
    const float* __restrict__ A, const float* __restrict__ W,
    float* __restrict__ out0, float* __restrict__ out1,
    int M, int N, int K, int mode)
{
  __shared__ float As[32][68];
  __shared__ float Bs[32][68];
  const int m0 = blockIdx.x * 64;
  const int n0 = blockIdx.y * 64;
  const int t  = threadIdx.x;
  const int tx = t & 15, ty = t >> 4;
  const int kk_s = t & 31, row_s = t >> 5;

  float acc[4][4] = {};

  for (int k0 = 0; k0 < K; k0 += 32) {
#pragma unroll
    for (int p = 0; p < 8; ++p) {
      int r = row_s + p * 8;
      As[kk_s][r] = A[(size_t)(m0 + r) * K + (k0 + kk_s)];
      Bs[kk_s][r] = W[(size_t)(n0 + r) * K + (k0 + kk_s)];
    }
    __syncthreads();
#pragma unroll
    for (int kk = 0; kk < 32; ++kk) {
      float4 a4 = *(const float4*)&As[kk][ty * 4];
      float4 b4 = *(const float4*)&Bs[kk][tx * 4];
      float av[4] = {a4.x, a4.y, a4.z, a4.w};
      float bv[4] = {b4.x, b4.y, b4.z, b4.w};
#pragma unroll
      for (int i = 0; i < 4; ++i)
#pragma unroll
        for (int j = 0; j < 4; ++j)
          acc[i][j] = fmaf(av[i], bv[j], acc[i][j]);
    }
    __syncthreads();
  }

#pragma unroll
  for (int i = 0; i < 4; ++i) {
    int m = m0 + ty * 4 + i;
    float4 c4 = make_float4(acc[i][0], acc[i][1], acc[i][2], acc[i][3]);
    if (mode == 0) {
      *(float4*)&out0[(size_t)m * N + n0 + tx * 4] = c4;
    } else {
      int n = n0 + tx * 4;
      if (n < 256) {
        *(float4*)&out0[(size_t)m * 256 + n] = c4;
      } else {
        c4.x = silu_f(c4.x); c4.y = silu_f(c4.y);
        c4.z = silu_f(c4.z); c4.w = silu_f(c4.w);
        *(float4*)&out1[(size_t)m * 256 + (n - 256)] = c4;
      }
    }
  }
}

// ---------------------------------------------------------------------------
// Causal depthwise conv (k=4) + bias + silu, with [M,256] -> [B,256,L] transpose
// ---------------------------------------------------------------------------
__global__ __launch_bounds__(256) void conv_silu_t(
    const float* __restrict__ xa_rm,   // [M,256]
    const float* __restrict__ cw,      // [256,4]
    const float* __restrict__ cb,      // [256]
    float* __restrict__ xa_t)          // [B,256,L]
{
  __shared__ float tile[64][133];      // [dd][li], li=0 ~ l0-3
  __shared__ float s_cw[64][4];
  __shared__ float s_cb[64];
  const int b  = blockIdx.z;
  const int d0 = blockIdx.y * 64;
  const int l0 = blockIdx.x * 128;
  const int t  = threadIdx.x;

  if (t < 64) {
    s_cb[t] = cb[d0 + t];
#pragma unroll
    for (int k = 0; k < 4; ++k) s_cw[t][k] = cw[(d0 + t) * 4 + k];
  }
  const int dd_st = t & 63;
  for (int li = t >> 6; li < 131; li += 4) {
    int l = l0 - 3 + li;
    float v = 0.f;
    if (l >= 0) v = xa_rm[((size_t)(b * LSEQ + l)) * 256 + d0 + dd_st];
    tile[dd_st][li] = v;
  }
  __syncthreads();

  for (int idx = t; idx < 64 * 128; idx += 256) {
    int dd = idx >> 7;
    int lc = idx & 127;
    float v = s_cb[dd]
            + tile[dd][lc + 0] * s_cw[dd][0]
            + tile[dd][lc + 1] * s_cw[dd][1]
            + tile[dd][lc + 2] * s_cw[dd][2]
            + tile[dd][lc + 3] * s_cw[dd][3];
    v = silu_f(v);
    xa_t[((size_t)(b * DINNER + d0 + dd)) * LSEQ + l0 + lc] = v;
  }
}

// ---------------------------------------------------------------------------
// Fused x_proj (40x256) + dt_proj (256x8) + softplus.
// Writes dt_t [B,256,L], Bt/Ct [B,16,L]  (state-major, L-contiguous).
// ---------------------------------------------------------------------------
__global__ __launch_bounds__(256) void proj_dt(
    const float* __restrict__ xa_t,    // [B,256,L]
    const float* __restrict__ xp_w,    // [40,256]
    const float* __restrict__ dtp_w,   // [256,8]
    const float* __restrict__ dtp_b,   // [256]
    float* __restrict__ dt_t,          // [B,256,L]
    float* __restrict__ Bt,            // [B,16,L]
    float* __restrict__ Ct)            // [B,16,L]
{
  __shared__ float s_xpc[40][68];
  __shared__ float s_dtw[256 * 8];
  __shared__ float s_dtb[256];
  __shared__ float s_xa[64][68];
  __shared__ float s_proj[64][44];
  const int b  = blockIdx.y;
  const int l0 = blockIdx.x * 64;
  const int t  = threadIdx.x;

  for (int i = t; i < 256 * 8; i += 256) s_dtw[i] = dtp_w[i];
  s_dtb[t] = dtp_b[t];

  const int ll_st  = t & 63;
  const int kk0_st = t >> 6;
  const int kk_w   = t & 63;
  const int nb_w   = t >> 6;
  const int lA = t & 31;
  const int g  = t >> 5;

  float acc0[5] = {}, acc1[5] = {};

  for (int kc = 0; kc < 256; kc += 64) {
    __syncthreads();
#pragma unroll
    for (int p = 0; p < 16; ++p) {
      int kk = kk0_st + p * 4;
      s_xa[ll_st][kk] =
          xa_t[((size_t)(b * DINNER + kc + kk)) * LSEQ + l0 + ll_st];
    }
#pragma unroll
    for (int p = 0; p < 10; ++p) {
      int n = nb_w + p * 4;
      s_xpc[n][kk_w] = xp_w[n * 256 + kc + kk_w];
    }
    __syncthreads();
#pragma unroll
    for (int kk = 0; kk < 64; kk += 4) {
      float4 a0 = *(const float4*)&s_xa[lA][kk];
      float4 a1 = *(const float4*)&s_xa[lA + 32][kk];
#pragma unroll
      for (int j = 0; j < 5; ++j) {
        float4 w4 = *(const float4*)&s_xpc[g * 5 + j][kk];
        acc0[j] = fmaf(a0.x, w4.x, fmaf(a0.y, w4.y,
                  fmaf(a0.z, w4.z, fmaf(a0.w, w4.w, acc0[j]))));
        acc1[j] = fmaf(a1.x, w4.x, fmaf(a1.y, w4.y,
                  fmaf(a1.z, w4.z, fmaf(a1.w, w4.w, acc1[j]))));
      }
    }
  }
  __syncthreads();
#pragma unroll
  for (int j = 0; j < 5; ++j) {
    s_proj[lA][g * 5 + j]      = acc0[j];
    s_proj[lA + 32][g * 5 + j] = acc1[j];
  }
  __syncthreads();

  const int ll = t & 63;
  const int dgroup = t >> 6;
  float4 p0 = *(const float4*)&s_proj[ll][0];
  float4 p1 = *(const float4*)&s_proj[ll][4];
  for (int j = 0; j < 64; ++j) {
    int dout = dgroup * 64 + j;
    float4 w0 = *(const float4*)&s_dtw[dout * 8];
    float4 w1 = *(const float4*)&s_dtw[dout * 8 + 4];
    float v = s_dtb[dout]
            + p0.x * w0.x + p0.y * w0.y + p0.z * w0.z + p0.w * w0.w
            + p1.x * w1.x + p1.y * w1.y + p1.z * w1.z + p1.w * w1.w;
    dt_t[((size_t)(b * DINNER + dout)) * LSEQ + l0 + ll] = softplus_f(v);
  }
  // Bt/Ct: [B,16,L] — 64 consecutive l-addresses per instruction (coalesced)
  if (t < 64) {
#pragma unroll
    for (int nn = 0; nn < 16; ++nn)
      Bt[((size_t)(b * NSTATE + nn)) * LSEQ + l0 + t] = s_proj[t][8 + nn];
  } else if (t < 128) {
    int lw = t - 64;
#pragma unroll
    for (int nn = 0; nn < 16; ++nn)
      Ct[((size_t)(b * NSTATE + nn)) * LSEQ + l0 + lw] = s_proj[lw][24 + nn];
  }
}

// ---------------------------------------------------------------------------
// Selective scan — EXACT sequential order (same math as the R0 kernel that
// passed at 1.4e-11). 16 lanes (one per state n) per (b,d) channel; 4
// channels/wave. Deep register double-buffering: 16-step groups, all 16
// float4 loads of group g+1 issued before computing group g.
// grid: BATCH * DINNER/4 = 512 blocks of 64 threads.
// ---------------------------------------------------------------------------
__global__ __launch_bounds__(64) void scan_k(
    const float* __restrict__ dt_t, const float* __restrict__ u_t,
    const float* __restrict__ Bt,   const float* __restrict__ Ct,
    const float* __restrict__ A_log, const float* __restrict__ Dp,
    float* __restrict__ y_t)
{
  const int blk = blockIdx.x;
  const int b   = blk >> 6;
  const int d0  = (blk & 63) * 4;
  const int lane = threadIdx.x;
  const int g = lane >> 4;
  const int n = lane & 15;
  const int d = d0 + g;

  const float Aa = -expf(A_log[d * NSTATE + n]);
  const float Dv = Dp[d];
  const float4* dtp = (const float4*)(dt_t + ((size_t)(b * DINNER + d)) * LSEQ);
  const float4* up  = (const float4*)(u_t  + ((size_t)(b * DINNER + d)) * LSEQ);
  const float4* Bp  = (const float4*)(Bt + ((size_t)(b * NSTATE + n)) * LSEQ);
  const float4* Cp  = (const float4*)(Ct + ((size_t)(b * NSTATE + n)) * LSEQ);
  float4* yp = (float4*)(y_t + ((size_t)(b * DINNER + d)) * LSEQ);

  const int NG = LSEQ / 16;            // 256 groups of 16 steps
  float4 Rd[2][4], Ru[2][4], Rb[2][4], Rc[2][4];
  float h = 0.f;

#define LOAD_GRP(s, grp) do {                                            \
    int _base = (grp) * 4;                                               \
    _Pragma("unroll")                                                    \
    for (int q = 0; q < 4; ++q) {                                        \
      Rd[s][q] = dtp[_base + q];  Ru[s][q] = up[_base + q];              \
      Rb[s][q] = Bp[_base + q];   Rc[s][q] = Cp[_base + q];              \
    }                                                                    \
  } while (0)

#define COMP_GRP(s, grp) do {                                            \
    _Pragma("unroll")                                                    \
    for (int q = 0; q < 4; ++q) {                                        \
      float dts[4] = {Rd[s][q].x, Rd[s][q].y, Rd[s][q].z, Rd[s][q].w};   \
      float us[4]  = {Ru[s][q].x, Ru[s][q].y, Ru[s][q].z, Ru[s][q].w};   \
      float bv[4]  = {Rb[s][q].x, Rb[s][q].y, Rb[s][q].z, Rb[s][q].w};   \
      float cv[4]  = {Rc[s][q].x, Rc[s][q].y, Rc[s][q].z, Rc[s][q].w};   \
      float ys[4];                                                       \
      _Pragma("unroll")                                                  \
      for (int st = 0; st < 4; ++st) {                                   \
        float a = expf(dts[st] * Aa);                                    \
        h = fmaf(a, h, (dts[st] * us[st]) * bv[st]);                     \
        float p = h * cv[st];                                            \
        p += __shfl_xor(p, 1);                                           \
        p += __shfl_xor(p, 2);                                           \
        p += __shfl_xor(p, 4);                                           \
        p += __shfl_xor(p, 8);                                           \
        ys[st] = fmaf(us[st], Dv, p);                                    \
      }                                                                  \
      if (n == 0)                                                        \
        yp[(grp) * 4 + q] = make_float4(ys[0], ys[1], ys[2], ys[3]);     \
    }                                                                    \
  } while (0)

  LOAD_GRP(0, 0);
  for (int it = 0; it < NG; it += 2) {
    int nx1 = (it + 1 < NG) ? it + 1 : NG - 1;
    LOAD_GRP(1, nx1);
    COMP_GRP(0, it);
    int nx2 = (it + 2 < NG) ? it + 2 : NG - 1;
    LOAD_GRP(0, nx2);
    COMP_GRP(1, it + 1);
  }
#undef LOAD_GRP
#undef COMP_GRP
}

// ---------------------------------------------------------------------------
// ymul[m,d] = y_t[b,d,l] * zs[m,d]   ([B,256,L] -> [M,256] transpose, fused mul)
// ---------------------------------------------------------------------------
__global__ __launch_bounds__(256) void transmul(
    const float* __restrict__ y_t, const float* __restrict__ zs,
    float* __restrict__ outA)
{
  __shared__ float tile[64][129];
  const int b  = blockIdx.z;
  const int d0 = blockIdx.y * 64;
  const int l0 = blockIdx.x * 128;
  const int t  = threadIdx.x;
  const int lc_st = t & 127;
  for (int dd = t >> 7; dd < 64; dd += 2)
    tile[dd][lc_st] = y_t[((size_t)(b * DINNER + d0 + dd)) * LSEQ + l0 + lc_st];
  __syncthreads();
  for (int idx = t; idx < 64 * 128; idx += 256) {
    int dd = idx & 63, lc = idx >> 6;
    size_t addr = ((size_t)(b * LSEQ) + l0 + lc) * DINNER + d0 + dd;
    outA[addr] = tile[dd][lc] * zs[addr];
  }
}

// ---------------------------------------------------------------------------
extern "C" void kernel_launch(void* const* d_in, const int* in_sizes, int n_in,
                              void* d_out, int out_size, void* d_ws, size_t ws_size,
                              hipStream_t stream) {
  const float* x_in  = (const float*)d_in[0];
  const float* w_in  = (const float*)d_in[1];   // [4,512,128]
  const float* cw    = (const float*)d_in[2];   // [4,256,4]
  const float* cb    = (const float*)d_in[3];   // [4,256]
  const float* xpw   = (const float*)d_in[4];   // [4,40,256]
  const float* dtw   = (const float*)d_in[5];   // [4,256,8]
  const float* dtb   = (const float*)d_in[6];   // [4,256]
  const float* alog  = (const float*)d_in[7];   // [4,256,16]
  const float* Dp    = (const float*)d_in[8];   // [4,256]
  const float* ow    = (const float*)d_in[9];   // [4,128,256]
  float* out = (float*)d_out;

  const size_t M = MROWS;
  float* f0 = (float*)d_ws;            // x ping  [M,128]
  float* f1 = f0 + M * 128;            // x pong  [M,128]
  float* f2 = f1 + M * 128;            // xa_pre -> dt_t [B,256,L]
  float* f3 = f2 + M * 256;            // zs = silu(z) [M,256]
  float* f4 = f3 + M * 256;            // xa_t [B,256,L] -> later ymul [M,256]
  float* f6 = f4 + M * 256;            // Bt [B,16,L]
  float* f7 = f6 + M * 16;             // Ct [B,16,L]
  float* f8 = f7 + M * 16;             // y_t [B,256,L]

  const float* cur = x_in;
  for (int i = 0; i < NLAYER; ++i) {
    float* xout = (i == NLAYER - 1) ? out : ((i % 2 == 0) ? f0 : f1);
    const float* wi  = w_in + (size_t)i * 512 * 128;
    const float* cwi = cw   + (size_t)i * 256 * 4;
    const float* cbi = cb   + (size_t)i * 256;
    const float* xpi = xpw  + (size_t)i * 40 * 256;
    const float* dwi = dtw  + (size_t)i * 256 * 8;
    const float* dbi = dtb  + (size_t)i * 256;
    const float* ali = alog + (size_t)i * 256 * 16;
    const float* dpi = Dp   + (size_t)i * 256;
    const float* owi = ow   + (size_t)i * 128 * 256;

    // 1. in_proj: [M,128]@[512,128]^T -> xa_pre(f2), silu(z)(f3)
    gemm_awt<<<dim3(MROWS / 64, 8), 256, 0, stream>>>(
        cur, wi, f2, f3, MROWS, 512, 128, 1);
    // 2. conv + silu + transpose -> xa_t (f4)
    conv_silu_t<<<dim3(LSEQ / 128, DINNER / 64, BATCH), 256, 0, stream>>>(
        f2, cwi, cbi, f4);
    // 3. x_proj + dt_proj + softplus -> dt_t(f2), Bt(f6), Ct(f7)
    proj_dt<<<dim3(LSEQ / 64, BATCH), 256, 0, stream>>>(
        f4, xpi, dwi, dbi, f2, f6, f7);
    // 4. selective scan (exact sequential) -> y_t (f8)
    scan_k<<<dim3(BATCH * DINNER / 4), 64, 0, stream>>>(
        f2, f4, f6, f7, ali, dpi, f8);
    // 5. y * silu(z), transpose back -> ymul (f4)
    transmul<<<dim3(LSEQ / 128, DINNER / 64, BATCH), 256, 0, stream>>>(
        f8, f3, f4);
    // 6. out_proj: [M,256]@[128,256]^T -> xout
    gemm_awt<<<dim3(MROWS / 64, 2), 256, 0, stream>>>(
        f4, owi, xout, nullptr, MROWS, 128, 256, 0);

    cur = xout;
  }
}